// Round 5
// baseline (111.524 us; speedup 1.0000x reference)
//
#include <hip/hip_runtime.h>

#define OUTS 7
#define CC 256
#define HH 56
#define WW 56
#define SPLIT 4   // ROI-list split factor: blocks per (image, channel) plane

// One block per (image n, channel c, roi-chunk s). Plane staged to LDS once
// per block (L3-resident, cheap). Lane = bin index (0..48); one ROI per
// wave-pass. ROIs are strided across the 4 chunk-blocks x 4 waves
// (list position m % 16 == s + 4*wave) to spread the heaviest image's work
// across CUs (R3 bottleneck: 1 block/CU straggler phase).
//
// R4 bug fix: the list MUST be built in a deterministic order identical
// across sibling blocks -- atomicAdd compaction is not. Wave 0 compacts in
// ascending-r order via ballot + prefix popcount.
__global__ __launch_bounds__(256) void roipool_kernel(
    const float* __restrict__ images, const float* __restrict__ rois,
    const int* __restrict__ roi_idx, float* __restrict__ out, int R)
{
    __shared__ float plane[HH * WW + 16];
    __shared__ int   list[256];            // ROI indices for this image
    __shared__ int   cnt;

    const int b = blockIdx.x;
    const int s = b & (SPLIT - 1);         // roi-chunk id 0..3
    const int pc = b >> 2;                 // plane id = n*CC + c
    const int n = pc / CC;
    const int c = pc % CC;
    const int t = threadIdx.x;

    // Deterministic compaction (ascending r), wave 0 only. R == 256 = 4*64.
    if (t < 64) {
        int base = 0;
        #pragma unroll
        for (int k = 0; k < 4; ++k) {
            int r = k * 64 + t;
            bool match = (r < R) && (roi_idx[r] == n);
            unsigned long long mask = __ballot(match);
            if (match) {
                int pos = base + __popcll(mask & ((1ULL << t) - 1ULL));
                list[pos] = r;
            }
            base += __popcll(mask);
        }
        if (t == 0) cnt = base;
    }

    // Stage plane -> LDS, coalesced 16B loads (784 float4 / 256 threads).
    const float4* src = reinterpret_cast<const float4*>(
        images + (size_t)pc * (HH * WW));
    float4* dst = reinterpret_cast<float4*>(plane);
    #pragma unroll
    for (int k = 0; k < 4; ++k) {
        int idx = t + k * 256;
        if (idx < (HH * WW) / 4) dst[idx] = src[idx];
    }

    __syncthreads();

    const int count = cnt;
    const int wv   = t >> 6;        // wave id 0..3
    const int lane = t & 63;
    const int i = lane / OUTS;      // bin row (lane < 49)
    const int j = lane - i * OUTS;  // bin col

    // (chunk s, wave wv) takes list positions m % 16 == s + 4*wv.
    for (int m = (wv << 2) + s; m < count; m += SPLIT * 4) {
        int r = list[m];
        if (lane >= OUTS * OUTS) continue;

        float4 rv = reinterpret_cast<const float4*>(rois)[r];
        int x1 = (int)floorf(rv.x * (float)WW);
        int y1 = (int)floorf(rv.y * (float)HH);
        int x2 = (int)ceilf (rv.z * (float)WW);
        int y2 = (int)ceilf (rv.w * (float)HH);
        int Hr = y2 - y1;
        int Wr = x2 - x1;

        int sy = y1 + (i * Hr) / OUTS;
        int ey = y1 + ((i + 1) * Hr + OUTS - 1) / OUTS;
        int sx = x1 + (j * Wr) / OUTS;
        int ex = x1 + ((j + 1) * Wr + OUTS - 1) / OUTS;

        float mx = -3.402823466e+38f;   // finfo(float32).min (empty-bin value)
        for (int y = sy; y < ey; ++y) {
            const float* row = plane + y * WW;
            for (int x = sx; x < ex; ++x)
                mx = fmaxf(mx, row[x]);
        }
        out[((size_t)r * CC + c) * (OUTS * OUTS) + lane] = mx;
    }
}

extern "C" void kernel_launch(void* const* d_in, const int* in_sizes, int n_in,
                              void* d_out, int out_size, void* d_ws, size_t ws_size,
                              hipStream_t stream) {
    const float* images  = (const float*)d_in[0];
    const float* rois    = (const float*)d_in[1];
    const int*   roi_idx = (const int*)d_in[2];
    float* out = (float*)d_out;

    int R = in_sizes[2];                         // 256
    int N = in_sizes[0] / (CC * HH * WW);        // 8

    int grid = N * CC * SPLIT;                   // 8192 blocks
    roipool_kernel<<<grid, 256, 0, stream>>>(images, rois, roi_idx, out, R);
}

// Round 6
// 95.845 us; speedup vs baseline: 1.1636x; 1.1636x over previous
//
#include <hip/hip_runtime.h>

#define OUTS 7
#define CC 256
#define HH 56
#define WW 56
#define PX (HH * WW)   // 3136
#define SPLIT 2        // ROI-list split across sibling blocks

// One block per (image n, channel-PAIR cpair, roi-chunk s). The two planes
// are staged INTERLEAVED as float2 in LDS so one ds_read_b64 + 2 fmax
// yields 2 outputs (halves pass count + loop overhead). Per-ROI adaptive
// bin edges are precomputed once per block into packed ushort tables --
// R2-R5 recomputed them (4 int divides + floorf/ceilf, ~50 VALU) on EVERY
// of the 65536 wave-passes, which pinned dur_us at ~47us regardless of
// occupancy/fetch changes.
__global__ __launch_bounds__(256) void roipool_kernel(
    const float* __restrict__ images, const float* __restrict__ rois,
    const int* __restrict__ roi_idx, float* __restrict__ out, int R)
{
    __shared__ float2 plane2[PX + 8];            // 25.2 KB, (c0,c1) per pixel
    __shared__ int    list[256];                 // deterministic ROI list
    __shared__ unsigned short ys[256 * 7];       // sy | ey<<8 per (m,i)
    __shared__ unsigned short xs[256 * 7];       // sx | ex<<8 per (m,j)
    __shared__ int cnt;

    const int b     = blockIdx.x;
    const int s     = b & (SPLIT - 1);
    const int pp    = b >> 1;          // n*128 + cpair
    const int n     = pp >> 7;
    const int cpair = pp & 127;
    const int c0    = cpair * 2;
    const int t     = threadIdx.x;

    // Deterministic ascending-r compaction (wave 0): identical list order
    // across sibling blocks (atomicAdd order is not -- R4 bug).
    if (t < 64) {
        int base = 0;
        #pragma unroll
        for (int k = 0; k < 4; ++k) {
            int r = k * 64 + t;
            bool match = (r < R) && (roi_idx[r] == n);
            unsigned long long mask = __ballot(match);
            if (match) list[base + __popcll(mask & ((1ULL << t) - 1ULL))] = r;
            base += __popcll(mask);
        }
        if (t == 0) cnt = base;
    }

    // Stage both planes, zipped: plane2[px] = (A[px], B[px]).
    const float4* srcA = reinterpret_cast<const float4*>(images + (size_t)(n * CC + c0)     * PX);
    const float4* srcB = reinterpret_cast<const float4*>(images + (size_t)(n * CC + c0 + 1) * PX);
    #pragma unroll
    for (int k = 0; k < 4; ++k) {
        int idx = t + k * 256;
        if (idx < PX / 4) {
            float4 a = srcA[idx];
            float4 bb = srcB[idx];
            float4* dst = reinterpret_cast<float4*>(&plane2[idx * 4]);
            dst[0] = make_float4(a.x, bb.x, a.y, bb.y);
            dst[1] = make_float4(a.z, bb.z, a.w, bb.w);
        }
    }

    __syncthreads();

    const int count = cnt;

    // Edge tables: e = m*7 + i; same formula serves rows (ys) and cols (xs).
    for (int e = t; e < count * 7; e += 256) {
        int m = e / 7, i = e - m * 7;
        int r = list[m];
        float4 rv = reinterpret_cast<const float4*>(rois)[r];
        int x1 = (int)floorf(rv.x * (float)WW);
        int y1 = (int)floorf(rv.y * (float)HH);
        int x2 = (int)ceilf (rv.z * (float)WW);
        int y2 = (int)ceilf (rv.w * (float)HH);
        int Hr = y2 - y1, Wr = x2 - x1;
        int sy = y1 + (i * Hr) / 7, ey = y1 + ((i + 1) * Hr + 6) / 7;
        int sx = x1 + (i * Wr) / 7, ex = x1 + ((i + 1) * Wr + 6) / 7;
        ys[m * 7 + i] = (unsigned short)(sy | (ey << 8));
        xs[m * 7 + i] = (unsigned short)(sx | (ex << 8));
    }

    __syncthreads();

    const int wv   = t >> 6;
    const int lane = t & 63;
    const int i = lane / 7;          // bin row (valid for lane < 49)
    const int j = lane - i * 7;      // bin col

    // (chunk s, wave wv) takes list positions m % 8 == s + 2*wv.
    for (int m = (wv << 1) + s; m < count; m += SPLIT * 4) {
        if (lane >= OUTS * OUTS) continue;
        int r = list[m];
        int yse = ys[m * 7 + i];
        int xse = xs[m * 7 + j];
        int sy = yse & 255, ey = yse >> 8;
        int sx = xse & 255, ex = xse >> 8;

        float a0 = -3.402823466e+38f;   // finfo(float32).min (empty-bin value)
        float a1 = a0;
        for (int y = sy; y < ey; ++y) {
            const float2* row = plane2 + y * WW;
            for (int x = sx; x < ex; ++x) {
                float2 v = row[x];      // ds_read_b64: 2 channels at once
                a0 = fmaxf(a0, v.x);
                a1 = fmaxf(a1, v.y);
            }
        }
        size_t o = ((size_t)r * CC + c0) * (OUTS * OUTS) + lane;
        out[o] = a0;
        out[o + OUTS * OUTS] = a1;      // channel c0+1
    }
}

extern "C" void kernel_launch(void* const* d_in, const int* in_sizes, int n_in,
                              void* d_out, int out_size, void* d_ws, size_t ws_size,
                              hipStream_t stream) {
    const float* images  = (const float*)d_in[0];
    const float* rois    = (const float*)d_in[1];
    const int*   roi_idx = (const int*)d_in[2];
    float* out = (float*)d_out;

    int R = in_sizes[2];                         // 256
    int N = in_sizes[0] / (CC * HH * WW);        // 8

    int grid = N * (CC / 2) * SPLIT;             // 2048 blocks
    roipool_kernel<<<grid, 256, 0, stream>>>(images, rois, roi_idx, out, R);
}